// Round 2
// baseline (4592.799 us; speedup 1.0000x reference)
//
#include <hip/hip_runtime.h>
#include <hip/hip_bf16.h>

// ContinuousLSTMLayer: B=256,S=512,F=64,H=128, 4 ODE steps x RK4 per time step.
// ALL inputs/outputs are float32 (per reference dtypes; round-1 NaN was caused
// by misreading f32 buffers as bf16 -> NaN-pattern weights).
// Persistent kernel: 1 block per batch row (256 blocks x 256 threads, 4 waves).
// Recurrent weights held in VGPRs as packed f16 pairs; h exchanged via
// double-buffered f16 LDS (1 barrier/stage); dots via v_dot2_f32_f16.
// Recurrence carrier (h0v/c0v) stays f32 per-lane: f16 only perturbs gate
// preactivations (~1e-4), not the integrated state.

#define B_N 256
#define S_N 512
#define F_N 64
#define H_N 128

typedef _Float16 h2_t __attribute__((ext_vector_type(2)));

__device__ __forceinline__ unsigned int packh2(float a, float b) {
  h2_t v;
  v.x = (_Float16)a;
  v.y = (_Float16)b;
  return __builtin_bit_cast(unsigned int, v);
}

__device__ __forceinline__ float fdot2u(unsigned int a, unsigned int b, float c) {
#if __has_builtin(__builtin_amdgcn_fdot2)
  return __builtin_amdgcn_fdot2(__builtin_bit_cast(h2_t, a),
                                __builtin_bit_cast(h2_t, b), c, false);
#else
  h2_t ha = __builtin_bit_cast(h2_t, a);
  h2_t hb = __builtin_bit_cast(h2_t, b);
  return fmaf((float)ha.x, (float)hb.x, fmaf((float)ha.y, (float)hb.y, c));
#endif
}

// sigmoid via exp2 + rcp (overflow-safe: rcp(inf)=0)
__device__ __forceinline__ float sigm(float x) {
  float e = __builtin_amdgcn_exp2f(-1.442695040888963f * x);
  return __builtin_amdgcn_rcpf(1.0f + e);
}

__global__ void __launch_bounds__(256, 1) clstm_persistent(
    const float* __restrict__ x,    // [B,S,F] f32
    const float* __restrict__ td,   // [B,S]   f32
    const float* __restrict__ Wi, const float* __restrict__ bi,
    const float* __restrict__ Wf, const float* __restrict__ bff,
    const float* __restrict__ Wo, const float* __restrict__ bo,
    const float* __restrict__ Wg, const float* __restrict__ bg,
    float* __restrict__ out)        // [B,S,H] f32
{
  const int b = blockIdx.x;
  const int t = threadIdx.x;
  const int w = t >> 6;        // wave 0..3
  const int l = t & 63;        // lane
  const int p = l & 1;         // 0: gates (i,f)  1: gates (o,g)
  const int n = (w << 5) + (l >> 1);  // h index 0..127, one lane-pair per n

  const float* W0 = p ? Wo : Wi;
  const float* W1 = p ? Wg : Wf;
  const float bias0 = (p ? bo : bi)[n];
  const float bias1 = (p ? bg : bff)[n];

  // Recurrent weight columns (rows 64..191 of W) as packed f16 k-pairs: 128 VGPRs
  // x-part weight columns (rows 0..63): 64 VGPRs
  unsigned int w0[64], w1[64], wx0[32], wx1[32];
#pragma unroll
  for (int k = 0; k < 64; ++k) {
    int r = (64 + 2 * k) * H_N + n;
    w0[k] = packh2(W0[r], W0[r + H_N]);
    w1[k] = packh2(W1[r], W1[r + H_N]);
  }
#pragma unroll
  for (int k = 0; k < 32; ++k) {
    int r = (2 * k) * H_N + n;
    wx0[k] = packh2(W0[r], W0[r + H_N]);
    wx1[k] = packh2(W1[r], W1[r + H_N]);
  }

  __shared__ alignas(16) _Float16 lds_h[2][H_N];  // double-buffered h (f16)
  __shared__ alignas(16) _Float16 lds_x[F_N];     // current x_t (f16 pairs)
  __shared__ float lds_td[S_N];                   // all time_diffs for this row

  // prologue staging
  lds_td[t] = td[b * S_N + t];
  lds_td[t + 256] = td[b * S_N + t + 256];
  if (t < 32) {
    const float* xr = x + (size_t)b * S_N * F_N;
    ((unsigned int*)lds_x)[t] = packh2(xr[2 * t], xr[2 * t + 1]);
  }
  lds_h[0][n] = (_Float16)0.0f;  // lane pairs write same value: benign
  __syncthreads();

  float h0v = 0.f, c0v = 0.f;      // RK base state (per-lane, for this n)
  float h_ev = 0.f, c_ev = 0.f;    // current evaluation point
  float sum_h = 0.f, sum_c = 0.f;  // RK accumulators
  const float scale = p ? 2.0f : 1.0f;   // p=1: a1 = tanh via 2*sig(2x)-1
  const float shiftc = scale - 1.0f;

  for (int s = 0; s < S_N; ++s) {
    float dt = fminf(lds_td[s], 1.0f) * 0.25f;  // MAX_DT / ODE_STEPS
    float hdt = 0.5f * dt;
    float d6 = dt * (1.0f / 6.0f);

    // x-projection + bias for this time step (reused by all 16 stages)
    float xp0 = bias0, xp1 = bias1;
    {
      const uint4* xv4 = (const uint4*)lds_x;
#pragma unroll
      for (int q = 0; q < 8; ++q) {
        uint4 hh = xv4[q];
        xp0 = fdot2u(hh.x, wx0[4*q+0], xp0); xp1 = fdot2u(hh.x, wx1[4*q+0], xp1);
        xp0 = fdot2u(hh.y, wx0[4*q+1], xp0); xp1 = fdot2u(hh.y, wx1[4*q+1], xp1);
        xp0 = fdot2u(hh.z, wx0[4*q+2], xp0); xp1 = fdot2u(hh.z, wx1[4*q+2], xp1);
        xp0 = fdot2u(hh.w, wx0[4*q+3], xp0); xp1 = fdot2u(hh.w, wx1[4*q+3], xp1);
      }
    }

    // prefetch next x row into registers (latency hidden by 16 stages)
    float xn0 = 0.f, xn1 = 0.f;
    if (t < 32 && s + 1 < S_N) {
      const float* xr = x + (size_t)(b * S_N + s + 1) * F_N;
      xn0 = xr[2 * t];
      xn1 = xr[2 * t + 1];
    }

#pragma unroll 1
    for (int ode = 0; ode < 4; ++ode) {
#pragma unroll
      for (int st = 0; st < 4; ++st) {
        // gate pre-activations: xp + h_ev @ W_h   (reads buffer st&1)
        float acc0 = xp0, acc1 = xp1;
        const uint4* hv4 = (const uint4*)lds_h[st & 1];
#pragma unroll
        for (int q = 0; q < 16; ++q) {
          uint4 hh = hv4[q];  // broadcast: all lanes same address
          acc0 = fdot2u(hh.x, w0[4*q+0], acc0); acc1 = fdot2u(hh.x, w1[4*q+0], acc1);
          acc0 = fdot2u(hh.y, w0[4*q+1], acc0); acc1 = fdot2u(hh.y, w1[4*q+1], acc1);
          acc0 = fdot2u(hh.z, w0[4*q+2], acc0); acc1 = fdot2u(hh.z, w1[4*q+2], acc1);
          acc0 = fdot2u(hh.w, w0[4*q+3], acc0); acc1 = fdot2u(hh.w, w1[4*q+3], acc1);
        }
        float a0 = sigm(acc0);                                // i or o
        float a1 = fmaf(scale, sigm(scale * acc1), -shiftc);  // f or tanh->g
        float q0 = __shfl_xor(a0, 1, 64);
        float q1 = __shfl_xor(a1, 1, 64);
        float gi = p ? q0 : a0;
        float gf = p ? q1 : a1;
        float go = p ? a0 : q0;
        float gg = p ? a1 : q1;
        float tc = fmaf(2.0f, sigm(2.0f * c_ev), -1.0f);      // tanh(c)
        float kc = fmaf(gi, gg, (gf - 1.0f) * c_ev);          // i*g + f*c - c
        float kh = fmaf(go, tc, -h_ev);                       // o*tanh(c) - h

        float h_nx, c_nx;
        if (st == 0) {
          sum_h = kh; sum_c = kc;
          h_nx = fmaf(hdt, kh, h0v); c_nx = fmaf(hdt, kc, c0v);
        } else if (st == 1) {
          sum_h = fmaf(2.f, kh, sum_h); sum_c = fmaf(2.f, kc, sum_c);
          h_nx = fmaf(hdt, kh, h0v); c_nx = fmaf(hdt, kc, c0v);
        } else if (st == 2) {
          sum_h = fmaf(2.f, kh, sum_h); sum_c = fmaf(2.f, kc, sum_c);
          h_nx = fmaf(dt, kh, h0v); c_nx = fmaf(dt, kc, c0v);
        } else {
          sum_h += kh; sum_c += kc;
          h0v = fmaf(d6, sum_h, h0v); c0v = fmaf(d6, sum_c, c0v);
          h_nx = h0v; c_nx = c0v;
        }

        // write other buffer; single barrier covers RAW (next read) and WAR
        lds_h[(st & 1) ^ 1][n] = (_Float16)h_nx;
        if (st == 3 && ode == 3) {
          if (t < 32 && s + 1 < S_N)
            ((unsigned int*)lds_x)[t] = packh2(xn0, xn1);
        }
        __syncthreads();
        h_ev = h_nx; c_ev = c_nx;
      }
    }

    if (p == 0) out[(size_t)(b * S_N + s) * H_N + n] = h0v;
  }
}

extern "C" void kernel_launch(void* const* d_in, const int* in_sizes, int n_in,
                              void* d_out, int out_size, void* d_ws, size_t ws_size,
                              hipStream_t stream) {
  (void)in_sizes; (void)n_in; (void)d_ws; (void)ws_size; (void)out_size;
  clstm_persistent<<<B_N, 256, 0, stream>>>(
      (const float*)d_in[0],  // x
      (const float*)d_in[1],  // time_diffs
      (const float*)d_in[2], (const float*)d_in[3],   // W_i, b_i
      (const float*)d_in[4], (const float*)d_in[5],   // W_f, b_f
      (const float*)d_in[6], (const float*)d_in[7],   // W_o, b_o
      (const float*)d_in[8], (const float*)d_in[9],   // W_g, b_g
      (float*)d_out);
}

// Round 3
// 4541.949 us; speedup vs baseline: 1.0112x; 1.0112x over previous
//
#include <hip/hip_runtime.h>

// ContinuousLSTMLayer: B=256,S=512,F=64,H=128, 4 ODE steps x RK4 = 8192
// sequential stages. Persistent: 1 block per batch row, 512 threads (8 waves,
// 2/SIMD for latency hiding). k-split x4 across lanes cuts the LDS h-broadcast
// from 64KB to 32KB per stage; ks-reduction via DPP quad_perm (VALU pipe) +
// one ds_swizzle xor4; gate-pair exchange via DPP. Tail split: ks{0,1} lanes
// integrate n, ks{2,3} integrate n+64. Weights as packed f16 pairs in VGPRs
// (96 regs); dots via v_dot2_f32_f16; RK carrier stays f32 per-lane.

#define B_N 256
#define S_N 512
#define F_N 64
#define H_N 128

typedef _Float16 h2_t __attribute__((ext_vector_type(2)));

static __device__ __forceinline__ unsigned int packh2(float a, float b) {
  h2_t v; v.x = (_Float16)a; v.y = (_Float16)b;
  return __builtin_bit_cast(unsigned int, v);
}
static __device__ __forceinline__ float fdot2u(unsigned int a, unsigned int b, float c) {
  return __builtin_amdgcn_fdot2(__builtin_bit_cast(h2_t, a),
                                __builtin_bit_cast(h2_t, b), c, false);
}
// sigmoid via exp2 + rcp (overflow-safe: rcp(inf)=0)
static __device__ __forceinline__ float sigm(float x) {
  float e = __builtin_amdgcn_exp2f(-1.442695040888963f * x);
  return __builtin_amdgcn_rcpf(1.0f + e);
}
// reduce over lane-bit1 (ks bit0): DPP quad_perm [2,3,0,1] — VALU pipe, no LDS
static __device__ __forceinline__ float red_xor2(float x) {
  int j = __builtin_amdgcn_mov_dpp(__builtin_bit_cast(int, x), 0x4E, 0xF, 0xF, true);
  return x + __builtin_bit_cast(float, j);
}
// reduce over lane-bit2 (ks bit1): ds_swizzle xor4 (within 32-lane half: ok)
static __device__ __forceinline__ float red_xor4(float x) {
  int j = __builtin_amdgcn_ds_swizzle(__builtin_bit_cast(int, x), 0x101F);
  return x + __builtin_bit_cast(float, j);
}
// exchange over lane-bit0 (gate pair): DPP quad_perm [1,0,3,2]
static __device__ __forceinline__ float exch_xor1(float x) {
  int j = __builtin_amdgcn_mov_dpp(__builtin_bit_cast(int, x), 0xB1, 0xF, 0xF, true);
  return __builtin_bit_cast(float, j);
}

__global__ void __launch_bounds__(512, 1) clstm_persistent(
    const float* __restrict__ x,    // [B,S,F] f32
    const float* __restrict__ td,   // [B,S]   f32
    const float* __restrict__ Wi, const float* __restrict__ bi,
    const float* __restrict__ Wf, const float* __restrict__ bff,
    const float* __restrict__ Wo, const float* __restrict__ bo,
    const float* __restrict__ Wg, const float* __restrict__ bg,
    float* __restrict__ out)        // [B,S,H] f32
{
  const int b = blockIdx.x;
  const int t = threadIdx.x;
  const int l = t & 63;
  const int p  = l & 1;         // gate-chain pair: 0 -> (i,f), 1 -> (o,g)
  const int ks = (l >> 1) & 3;  // k-split chunk
  const int n0 = t >> 3;        // 0..63
  const int n1 = n0 + 64;
  const bool hi_n   = (ks & 2) != 0;   // this lane integrates n1
  const int  na     = hi_n ? n1 : n0;
  const bool writer = (p == 0) && ((ks & 1) == 0);  // one writer per n

  const float* W0 = p ? Wo : Wi;   // chain 0 weights
  const float* W1 = p ? Wg : Wf;   // chain 1 weights

  // ---- weights into VGPRs: 4 chains (n0/n1 x chain0/1), k-chunk of 32 h-rows
  unsigned int w00[16], w01[16], w10[16], w11[16];   // recurrent (rows 64..191)
  unsigned int wx00[8], wx01[8], wx10[8], wx11[8];   // x-part   (rows 0..63)
#pragma unroll
  for (int k = 0; k < 16; ++k) {
    int r = (64 + ks * 32 + 2 * k) * H_N;
    w00[k] = packh2(W0[r + n0], W0[r + H_N + n0]);
    w01[k] = packh2(W1[r + n0], W1[r + H_N + n0]);
    w10[k] = packh2(W0[r + n1], W0[r + H_N + n1]);
    w11[k] = packh2(W1[r + n1], W1[r + H_N + n1]);
  }
#pragma unroll
  for (int k = 0; k < 8; ++k) {
    int r = (ks * 16 + 2 * k) * H_N;
    wx00[k] = packh2(W0[r + n0], W0[r + H_N + n0]);
    wx01[k] = packh2(W1[r + n0], W1[r + H_N + n0]);
    wx10[k] = packh2(W0[r + n1], W0[r + H_N + n1]);
    wx11[k] = packh2(W1[r + n1], W1[r + H_N + n1]);
  }
  // biases folded into xp init, applied only on ks==0 lanes
  const float bz  = (ks == 0) ? 1.0f : 0.0f;
  const float b00 = bz * (p ? bo : bi)[n0];
  const float b01 = bz * (p ? bg : bff)[n0];
  const float b10 = bz * (p ? bo : bi)[n1];
  const float b11 = bz * (p ? bg : bff)[n1];

  __shared__ alignas(16) _Float16 lds_h[2][H_N];       // double-buffered h
  __shared__ alignas(16) unsigned int lds_x[F_N / 2];  // x_t as packed f16 pairs
  __shared__ float lds_td[S_N];

  lds_td[t] = td[b * S_N + t];
  if (t < 32) {
    const float* xr = x + (size_t)b * S_N * F_N;
    lds_x[t] = packh2(xr[2 * t], xr[2 * t + 1]);
  }
  if (t < H_N) lds_h[0][t] = (_Float16)0.0f;
  __syncthreads();

  float h0v = 0.f, c0v = 0.f;      // RK base state for na
  float h_ev = 0.f, c_ev = 0.f;    // current evaluation point
  float sum_h = 0.f, sum_c = 0.f;  // RK accumulators
  const float scale  = p ? 2.0f : 1.0f;   // chain1: tanh via 2*sig(2x)-1
  const float shiftc = scale - 1.0f;

  for (int s = 0; s < S_N; ++s) {
    float dt  = fminf(lds_td[s], 1.0f) * 0.25f;  // MAX_DT / ODE_STEPS
    float hdt = 0.5f * dt;
    float d6  = dt * (1.0f / 6.0f);

    // x-projection partials (per-ks chunk; reduced together with h-dots)
    float xp00 = b00, xp01 = b01, xp10 = b10, xp11 = b11;
    {
      const uint4* xv = (const uint4*)(lds_x + ks * 8);
#pragma unroll
      for (int q = 0; q < 2; ++q) {
        uint4 hh = xv[q];
        xp00 = fdot2u(hh.x, wx00[4*q+0], xp00); xp01 = fdot2u(hh.x, wx01[4*q+0], xp01);
        xp10 = fdot2u(hh.x, wx10[4*q+0], xp10); xp11 = fdot2u(hh.x, wx11[4*q+0], xp11);
        xp00 = fdot2u(hh.y, wx00[4*q+1], xp00); xp01 = fdot2u(hh.y, wx01[4*q+1], xp01);
        xp10 = fdot2u(hh.y, wx10[4*q+1], xp10); xp11 = fdot2u(hh.y, wx11[4*q+1], xp11);
        xp00 = fdot2u(hh.z, wx00[4*q+2], xp00); xp01 = fdot2u(hh.z, wx01[4*q+2], xp01);
        xp10 = fdot2u(hh.z, wx10[4*q+2], xp10); xp11 = fdot2u(hh.z, wx11[4*q+2], xp11);
        xp00 = fdot2u(hh.w, wx00[4*q+3], xp00); xp01 = fdot2u(hh.w, wx01[4*q+3], xp01);
        xp10 = fdot2u(hh.w, wx10[4*q+3], xp10); xp11 = fdot2u(hh.w, wx11[4*q+3], xp11);
      }
    }

    // prefetch next x row (latency hidden by 16 stages)
    float xn0 = 0.f, xn1 = 0.f;
    if (t < 32 && s + 1 < S_N) {
      const float* xr = x + (size_t)(b * S_N + s + 1) * F_N;
      xn0 = xr[2 * t]; xn1 = xr[2 * t + 1];
    }

#pragma unroll 1
    for (int ode = 0; ode < 4; ++ode) {
#pragma unroll
      for (int st = 0; st < 4; ++st) {
        // partial dots over this lane's 32-element h chunk (4 chains)
        float A00 = xp00, A01 = xp01, A10 = xp10, A11 = xp11;
        const uint4* hv = (const uint4*)((const char*)lds_h[st & 1] + ks * 64);
#pragma unroll
        for (int q = 0; q < 4; ++q) {
          uint4 hh = hv[q];
          A00 = fdot2u(hh.x, w00[4*q+0], A00); A01 = fdot2u(hh.x, w01[4*q+0], A01);
          A10 = fdot2u(hh.x, w10[4*q+0], A10); A11 = fdot2u(hh.x, w11[4*q+0], A11);
          A00 = fdot2u(hh.y, w00[4*q+1], A00); A01 = fdot2u(hh.y, w01[4*q+1], A01);
          A10 = fdot2u(hh.y, w10[4*q+1], A10); A11 = fdot2u(hh.y, w11[4*q+1], A11);
          A00 = fdot2u(hh.z, w00[4*q+2], A00); A01 = fdot2u(hh.z, w01[4*q+2], A01);
          A10 = fdot2u(hh.z, w10[4*q+2], A10); A11 = fdot2u(hh.z, w11[4*q+2], A11);
          A00 = fdot2u(hh.w, w00[4*q+3], A00); A01 = fdot2u(hh.w, w01[4*q+3], A01);
          A10 = fdot2u(hh.w, w10[4*q+3], A10); A11 = fdot2u(hh.w, w11[4*q+3], A11);
        }
        // allreduce over ks (lane bits 1,2)
        A00 = red_xor2(A00); A01 = red_xor2(A01);
        A10 = red_xor2(A10); A11 = red_xor2(A11);
        A00 = red_xor4(A00); A01 = red_xor4(A01);
        A10 = red_xor4(A10); A11 = red_xor4(A11);
        // tail split: this lane integrates only na
        float A0 = hi_n ? A10 : A00;
        float A1 = hi_n ? A11 : A01;
        float a0 = sigm(A0);                                 // i or o
        float a1 = fmaf(scale, sigm(scale * A1), -shiftc);   // f or tanh->g
        float m0 = exch_xor1(a0);
        float m1 = exch_xor1(a1);
        float gi = p ? m0 : a0;
        float gf = p ? m1 : a1;
        float go = p ? a0 : m0;
        float gg = p ? a1 : m1;
        float tc = fmaf(2.0f, sigm(2.0f * c_ev), -1.0f);     // tanh(c)
        float kc = fmaf(gi, gg, (gf - 1.0f) * c_ev);         // i*g + f*c - c
        float kh = fmaf(go, tc, -h_ev);                      // o*tanh(c) - h

        float h_nx, c_nx;
        if (st == 0) {
          sum_h = kh; sum_c = kc;
          h_nx = fmaf(hdt, kh, h0v); c_nx = fmaf(hdt, kc, c0v);
        } else if (st == 1) {
          sum_h = fmaf(2.f, kh, sum_h); sum_c = fmaf(2.f, kc, sum_c);
          h_nx = fmaf(hdt, kh, h0v); c_nx = fmaf(hdt, kc, c0v);
        } else if (st == 2) {
          sum_h = fmaf(2.f, kh, sum_h); sum_c = fmaf(2.f, kc, sum_c);
          h_nx = fmaf(dt, kh, h0v); c_nx = fmaf(dt, kc, c0v);
        } else {
          sum_h += kh; sum_c += kc;
          h0v = fmaf(d6, sum_h, h0v); c0v = fmaf(d6, sum_c, c0v);
          h_nx = h0v; c_nx = c0v;
        }

        if (writer) lds_h[(st & 1) ^ 1][na] = (_Float16)h_nx;
        if (st == 3 && ode == 3) {
          if (t < 32 && s + 1 < S_N) lds_x[t] = packh2(xn0, xn1);
        }
        __syncthreads();
        h_ev = h_nx; c_ev = c_nx;
      }
    }

    if (writer) out[(size_t)(b * S_N + s) * H_N + na] = h0v;
  }
}

extern "C" void kernel_launch(void* const* d_in, const int* in_sizes, int n_in,
                              void* d_out, int out_size, void* d_ws, size_t ws_size,
                              hipStream_t stream) {
  (void)in_sizes; (void)n_in; (void)d_ws; (void)ws_size; (void)out_size;
  clstm_persistent<<<B_N, 512, 0, stream>>>(
      (const float*)d_in[0],  // x
      (const float*)d_in[1],  // time_diffs
      (const float*)d_in[2], (const float*)d_in[3],   // W_i, b_i
      (const float*)d_in[4], (const float*)d_in[5],   // W_f, b_f
      (const float*)d_in[6], (const float*)d_in[7],   // W_o, b_o
      (const float*)d_in[8], (const float*)d_in[9],   // W_g, b_g
      (float*)d_out);
}

// Round 4
// 3790.303 us; speedup vs baseline: 1.2117x; 1.1983x over previous
//
#include <hip/hip_runtime.h>

// ContinuousLSTMLayer B=256,S=512,F=64,H=128; 8192 sequential RK4 stages.
// MFMA version: stage GEMV [1x192]@[192x512] on the matrix pipe.
// Broadcast-A trick: all lanes read the same h-chunk from LDS, so every row
// of the A-tile equals h and every reg/lane of D equals the gate preact for
// n = 16*wave + (lane&15). Wave w owns n-range [16w,16w+16) for ALL 4 gates
// -> i,f,o,g land on the same lane; tail is uniform, no cross-lane ops, one
// barrier per stage. Weights resident as B-frags (f16) in VGPRs; x-projection
// MFMA'd once per time step and reused as the C operand (unified VGPR/AGPR).

#define B_N 256
#define S_N 512
#define F_N 64
#define H_N 128

typedef _Float16 v8h __attribute__((ext_vector_type(8)));
typedef float v4f __attribute__((ext_vector_type(4)));

// sigmoid via exp2 + rcp (overflow-safe: rcp(inf)=0)
static __device__ __forceinline__ float sigm(float x) {
  float e = __builtin_amdgcn_exp2f(-1.442695040888963f * x);
  return __builtin_amdgcn_rcpf(1.0f + e);
}

__global__ void __launch_bounds__(512, 2) clstm_mfma(
    const float* __restrict__ x,    // [B,S,F] f32
    const float* __restrict__ td,   // [B,S]   f32
    const float* __restrict__ Wi, const float* __restrict__ bi,
    const float* __restrict__ Wf, const float* __restrict__ bff,
    const float* __restrict__ Wo, const float* __restrict__ bo,
    const float* __restrict__ Wg, const float* __restrict__ bg,
    float* __restrict__ out)        // [B,S,H] f32
{
  const int b    = blockIdx.x;
  const int t    = threadIdx.x;
  const int wv   = t >> 6;     // wave 0..7 -> n-tile
  const int l    = t & 63;
  const int col  = l & 15;     // n within tile
  const int quad = l >> 4;     // k sub-chunk selector
  const int n    = wv * 16 + col;

  // ---- resident B-fragments: Bw[gate][ktile], ktile 0..5 over comb rows
  // (x rows 0..63 = kt 0,1; h rows 64..191 = kt 2..5). Lane holds
  // W[kt*32 + quad*8 + j][n] as 8 f16 (B[k][n], n=lane&15, k=quad*8+j).
  const float* Wptr[4] = {Wi, Wf, Wo, Wg};
  v8h Bw[4][6];
#pragma unroll
  for (int g = 0; g < 4; ++g) {
    const float* W = Wptr[g];
#pragma unroll
    for (int kt = 0; kt < 6; ++kt) {
      v8h f;
#pragma unroll
      for (int j = 0; j < 8; ++j)
        f[j] = (_Float16)W[(kt * 32 + quad * 8 + j) * H_N + n];
      Bw[g][kt] = f;
    }
  }
  v4f cb[4];  // bias as all-equal C operand
#pragma unroll
  for (int g = 0; g < 4; ++g) {
    float bv = (g == 0 ? bi : g == 1 ? bff : g == 2 ? bo : bg)[n];
    cb[g][0] = bv; cb[g][1] = bv; cb[g][2] = bv; cb[g][3] = bv;
  }

  __shared__ alignas(16) _Float16 lds_h[2][H_N];  // double-buffered h (f16)
  __shared__ alignas(16) _Float16 lds_x[F_N];     // current x_t (f16)
  __shared__ float lds_td[S_N];

  lds_td[t] = (t < S_N) ? td[b * S_N + t] : 0.f;
  if (t < 32) {
    const float* xr = x + (size_t)b * S_N * F_N;
    lds_x[2 * t]     = (_Float16)xr[2 * t];
    lds_x[2 * t + 1] = (_Float16)xr[2 * t + 1];
  }
  if (t < H_N) lds_h[0][t] = (_Float16)0.0f;
  __syncthreads();

  float h0v = 0.f, c0v = 0.f;      // RK base state for n (replicated x4 quads)
  float h_ev = 0.f, c_ev = 0.f;
  float sum_h = 0.f, sum_c = 0.f;
  const v4f zf = {0.f, 0.f, 0.f, 0.f};

  for (int s = 0; s < S_N; ++s) {
    float dt  = fminf(lds_td[s], 1.0f) * 0.25f;  // MAX_DT / ODE_STEPS
    float hdt = 0.5f * dt;
    float d6  = dt * (1.0f / 6.0f);

    // x-projection + bias once per time step: xpD[g] all-equal = bias + x@Wx
    v8h ax0 = *(const v8h*)(lds_x + quad * 8);
    v8h ax1 = *(const v8h*)(lds_x + 32 + quad * 8);
    v4f xpD[4];
#pragma unroll
    for (int g = 0; g < 4; ++g) {
      v4f a = __builtin_amdgcn_mfma_f32_16x16x32_f16(ax0, Bw[g][0], cb[g], 0, 0, 0);
      xpD[g] = __builtin_amdgcn_mfma_f32_16x16x32_f16(ax1, Bw[g][1], a, 0, 0, 0);
    }

    // prefetch next x row into regs (consumed at last stage of this step)
    float xn0 = 0.f, xn1 = 0.f;
    if (t < 32 && s + 1 < S_N) {
      const float* xr = x + (size_t)(b * S_N + s + 1) * F_N;
      xn0 = xr[2 * t]; xn1 = xr[2 * t + 1];
    }

#pragma unroll 1
    for (int ode = 0; ode < 4; ++ode) {
#pragma unroll
      for (int st = 0; st < 4; ++st) {
        const _Float16* hb = lds_h[st & 1];
        // broadcast A-frags: lane holds h[kt*32 + quad*8 + j]
        v8h ah0 = *(const v8h*)(hb + quad * 8);
        v8h ah1 = *(const v8h*)(hb + 32 + quad * 8);
        v8h ah2 = *(const v8h*)(hb + 64 + quad * 8);
        v8h ah3 = *(const v8h*)(hb + 96 + quad * 8);
        // per gate: two parallel depth-2 MFMA chains + final add
        float pre[4];
#pragma unroll
        for (int g = 0; g < 4; ++g) {
          v4f d0 = __builtin_amdgcn_mfma_f32_16x16x32_f16(ah0, Bw[g][2], xpD[g], 0, 0, 0);
          d0 = __builtin_amdgcn_mfma_f32_16x16x32_f16(ah1, Bw[g][3], d0, 0, 0, 0);
          v4f d1 = __builtin_amdgcn_mfma_f32_16x16x32_f16(ah2, Bw[g][4], zf, 0, 0, 0);
          d1 = __builtin_amdgcn_mfma_f32_16x16x32_f16(ah3, Bw[g][5], d1, 0, 0, 0);
          pre[g] = d0[0] + d1[0];
        }
        float ai = sigm(pre[0]);
        float af = sigm(pre[1]);
        float ao = sigm(pre[2]);
        float ag = fmaf(2.0f, sigm(2.0f * pre[3]), -1.0f);   // tanh
        float tc = fmaf(2.0f, sigm(2.0f * c_ev), -1.0f);     // tanh(c)
        float kc = fmaf(ai, ag, (af - 1.0f) * c_ev);         // i*g + f*c - c
        float kh = fmaf(ao, tc, -h_ev);                      // o*tanh(c) - h

        float h_nx, c_nx;
        if (st == 0) {
          sum_h = kh; sum_c = kc;
          h_nx = fmaf(hdt, kh, h0v); c_nx = fmaf(hdt, kc, c0v);
        } else if (st == 1) {
          sum_h = fmaf(2.f, kh, sum_h); sum_c = fmaf(2.f, kc, sum_c);
          h_nx = fmaf(hdt, kh, h0v); c_nx = fmaf(hdt, kc, c0v);
        } else if (st == 2) {
          sum_h = fmaf(2.f, kh, sum_h); sum_c = fmaf(2.f, kc, sum_c);
          h_nx = fmaf(dt, kh, h0v); c_nx = fmaf(dt, kc, c0v);
        } else {
          sum_h += kh; sum_c += kc;
          h0v = fmaf(d6, sum_h, h0v); c0v = fmaf(d6, sum_c, c0v);
          h_nx = h0v; c_nx = c0v;
        }

        if (quad == 0) lds_h[(st & 1) ^ 1][n] = (_Float16)h_nx;  // 128 writers
        if (st == 3 && ode == 3 && t < 32 && s + 1 < S_N) {
          lds_x[2 * t]     = (_Float16)xn0;
          lds_x[2 * t + 1] = (_Float16)xn1;
        }
        __syncthreads();
        h_ev = h_nx; c_ev = c_nx;
      }
    }

    if (quad == 0) out[(size_t)(b * S_N + s) * H_N + n] = h0v;
  }
}

extern "C" void kernel_launch(void* const* d_in, const int* in_sizes, int n_in,
                              void* d_out, int out_size, void* d_ws, size_t ws_size,
                              hipStream_t stream) {
  (void)in_sizes; (void)n_in; (void)d_ws; (void)ws_size; (void)out_size;
  clstm_mfma<<<B_N, 512, 0, stream>>>(
      (const float*)d_in[0],  // x
      (const float*)d_in[1],  // time_diffs
      (const float*)d_in[2], (const float*)d_in[3],   // W_i, b_i
      (const float*)d_in[4], (const float*)d_in[5],   // W_f, b_f
      (const float*)d_in[6], (const float*)d_in[7],   // W_o, b_o
      (const float*)d_in[8], (const float*)d_in[9],   // W_g, b_g
      (float*)d_out);
}